// Round 1
// baseline (386.101 us; speedup 1.0000x reference)
//
#include <hip/hip_runtime.h>

#define D 64
#define ED 16

// ---------------------------------------------------------------------------
// Probe: is edge_index int64 or int32?  If data is int64 (values < 2^31,
// nonnegative), every odd int32 half is 0.  Under int32 real indices, the
// probability that 8192 random indices in [0,1e5) are all zero is ~0.
// flag[0] = 1 -> int64, 0 -> int32.
// ---------------------------------------------------------------------------
__global__ void detect_idx64_kernel(const int* __restrict__ idx32, int* __restrict__ flag)
{
    __shared__ int any;
    if (threadIdx.x == 0) any = 0;
    __syncthreads();
    int v = 0;
    for (int i = threadIdx.x; i < 8192; i += blockDim.x)
        v |= idx32[2 * i + 1];
    if (v) atomicOr(&any, 1);
    __syncthreads();
    if (threadIdx.x == 0) flag[0] = (any == 0) ? 1 : 0;
}

// ---------------------------------------------------------------------------
// Edge phase: one 64-lane wave per edge.  lane d computes
//   m = x[src][d] + sum_k edge_attr[e][k] * W_e[k][d] + b_e[d]
// then atomicAdd into agg[dst][d]; lane 0 bumps cnt[dst].
// ---------------------------------------------------------------------------
__global__ void __launch_bounds__(256)
edge_scatter_kernel(const float* __restrict__ x,
                    const float* __restrict__ edge_attr,
                    const float* __restrict__ W_e,
                    const float* __restrict__ b_e,
                    const void* __restrict__ edge_index,
                    const int* __restrict__ flag,
                    float* __restrict__ agg,
                    float* __restrict__ cnt,
                    int n_edges)
{
    __shared__ float We[ED * D];
    __shared__ float be[D];
    for (int i = threadIdx.x; i < ED * D; i += blockDim.x) We[i] = W_e[i];
    if (threadIdx.x < D) be[threadIdx.x] = b_e[threadIdx.x];
    __syncthreads();

    const int is64 = flag[0];               // wave-uniform branch
    const int lane = threadIdx.x & 63;
    const int wid  = threadIdx.x >> 6;      // 0..3 (4 waves / block)
    const int estr = gridDim.x * 4;

    for (int e = blockIdx.x * 4 + wid; e < n_edges; e += estr) {
        int src, dst;
        if (is64) {
            src = (int)((const long long*)edge_index)[e];
            dst = (int)((const long long*)edge_index)[(size_t)n_edges + e];
        } else {
            src = ((const int*)edge_index)[e];
            dst = ((const int*)edge_index)[(size_t)n_edges + e];
        }
        const float4* ea = (const float4*)(edge_attr + (size_t)e * ED);
        float4 e0 = ea[0];
        float4 e1 = ea[1];
        float4 e2 = ea[2];
        float4 e3 = ea[3];

        float m = be[lane] + x[(size_t)src * D + lane];
        m += e0.x * We[ 0*D + lane] + e0.y * We[ 1*D + lane]
           + e0.z * We[ 2*D + lane] + e0.w * We[ 3*D + lane];
        m += e1.x * We[ 4*D + lane] + e1.y * We[ 5*D + lane]
           + e1.z * We[ 6*D + lane] + e1.w * We[ 7*D + lane];
        m += e2.x * We[ 8*D + lane] + e2.y * We[ 9*D + lane]
           + e2.z * We[10*D + lane] + e2.w * We[11*D + lane];
        m += e3.x * We[12*D + lane] + e3.y * We[13*D + lane]
           + e3.z * We[14*D + lane] + e3.w * We[15*D + lane];

        atomicAdd(&agg[(size_t)dst * D + lane], m);
        if (lane == 0) atomicAdd(&cnt[dst], 1.0f);
    }
}

// ---------------------------------------------------------------------------
// Node phase (in-place on d_out):
//   out[i][o] = (agg[i]/max(cnt[i],1)) . W_l[:,o] + b_l[o] + x[i] . W_r[:,o]
// 4 nodes per block-iteration, thread t -> (node t>>6, out-col t&63).
// W_l/W_r staged in LDS (32 KiB); rows staged per-iteration.
// ---------------------------------------------------------------------------
__global__ void __launch_bounds__(256)
node_kernel(const float* __restrict__ x,
            const float* __restrict__ aggc,   // == out (in-place)
            const float* __restrict__ cnt,
            const float* __restrict__ W_l,
            const float* __restrict__ b_l,
            const float* __restrict__ W_r,
            float* __restrict__ out,
            int n_nodes)
{
    __shared__ float Wl[D * D];
    __shared__ float Wr[D * D];
    __shared__ float bl[D];
    __shared__ float rowA[4 * D];
    __shared__ float rowX[4 * D];

    for (int i = threadIdx.x; i < D * D; i += blockDim.x) {
        Wl[i] = W_l[i];
        Wr[i] = W_r[i];
    }
    if (threadIdx.x < D) bl[threadIdx.x] = b_l[threadIdx.x];
    __syncthreads();

    const int o  = threadIdx.x & 63;
    const int il = threadIdx.x >> 6;      // 0..3
    const int n_tiles = (n_nodes + 3) / 4;

    for (int tile = blockIdx.x; tile < n_tiles; tile += gridDim.x) {
        const int base = tile * 4;
        const int node_of_t = base + (threadIdx.x >> 6);
        if (node_of_t < n_nodes) {
            float c = cnt[node_of_t];
            float s = 1.0f / fmaxf(c, 1.0f);
            rowA[threadIdx.x] = aggc[(size_t)base * D + threadIdx.x] * s;
            rowX[threadIdx.x] = x[(size_t)base * D + threadIdx.x];
        }
        __syncthreads();

        const int node = base + il;
        if (node < n_nodes) {
            float acc = bl[o];
            #pragma unroll
            for (int d = 0; d < D; ++d)
                acc += rowA[il * D + d] * Wl[d * D + o]
                     + rowX[il * D + d] * Wr[d * D + o];
            out[(size_t)node * D + o] = acc;
        }
        __syncthreads();   // protect row buffers before next iteration
    }
}

// ---------------------------------------------------------------------------
extern "C" void kernel_launch(void* const* d_in, const int* in_sizes, int n_in,
                              void* d_out, int out_size, void* d_ws, size_t ws_size,
                              hipStream_t stream)
{
    const float* x         = (const float*)d_in[0];
    const float* edge_attr = (const float*)d_in[1];
    const float* W_e       = (const float*)d_in[2];
    const float* b_e       = (const float*)d_in[3];
    const float* W_l       = (const float*)d_in[4];
    const float* b_l       = (const float*)d_in[5];
    const float* W_r       = (const float*)d_in[6];
    const void*  edge_index= d_in[7];

    const int n_nodes = in_sizes[0] / D;
    const int n_edges = in_sizes[1] / ED;

    float* out  = (float*)d_out;
    int*   flag = (int*)d_ws;
    float* cnt  = (float*)((char*)d_ws + 256);

    // agg accumulates directly in d_out; zero it + degree counts every call
    hipMemsetAsync(d_out, 0, (size_t)out_size * sizeof(float), stream);
    hipMemsetAsync(cnt, 0, (size_t)n_nodes * sizeof(float), stream);

    detect_idx64_kernel<<<1, 256, 0, stream>>>((const int*)edge_index, (int*)d_ws);

    edge_scatter_kernel<<<4096, 256, 0, stream>>>(
        x, edge_attr, W_e, b_e, edge_index, flag, out, cnt, n_edges);

    node_kernel<<<2048, 256, 0, stream>>>(
        x, out, cnt, W_l, b_l, W_r, out, n_nodes);
}

// Round 2
// 338.025 us; speedup vs baseline: 1.1422x; 1.1422x over previous
//
#include <hip/hip_runtime.h>

#define D 64
#define ED 16

// ---------------------------------------------------------------------------
// Probe: is edge_index int64 or int32?  flag[0] = 1 -> int64, 0 -> int32.
// ---------------------------------------------------------------------------
__global__ void detect_idx64_kernel(const int* __restrict__ idx32, int* __restrict__ flag)
{
    __shared__ int any;
    if (threadIdx.x == 0) any = 0;
    __syncthreads();
    int v = 0;
    for (int i = threadIdx.x; i < 8192; i += blockDim.x)
        v |= idx32[2 * i + 1];
    if (v) atomicOr(&any, 1);
    __syncthreads();
    if (threadIdx.x == 0) flag[0] = (any == 0) ? 1 : 0;
}

__device__ __forceinline__ int load_idx(const void* p, size_t i, int is64)
{
    return is64 ? (int)((const long long*)p)[i] : ((const int*)p)[i];
}

// ---------------------------------------------------------------------------
// CSR build step 1: per-destination degree count (1 int atomic per edge).
// ---------------------------------------------------------------------------
__global__ void __launch_bounds__(256)
count_kernel(const void* __restrict__ edge_index, const int* __restrict__ flag,
             int* __restrict__ cnt, int n_edges)
{
    const int is64 = flag[0];
    const int stride = gridDim.x * blockDim.x;
    for (int e = blockIdx.x * blockDim.x + threadIdx.x; e < n_edges; e += stride) {
        int dst = load_idx(edge_index, (size_t)n_edges + e, is64);
        atomicAdd(&cnt[dst], 1);
    }
}

// ---------------------------------------------------------------------------
// CSR build step 2: two-level exclusive scan of cnt -> offs.
// ---------------------------------------------------------------------------
__global__ void scan1_kernel(const int* __restrict__ cnt, int* __restrict__ offs,
                             int* __restrict__ bsum, int n)
{
    __shared__ int sd[256];
    const int t = threadIdx.x;
    const int i = blockIdx.x * 256 + t;
    int v = (i < n) ? cnt[i] : 0;
    sd[t] = v;
    __syncthreads();
    for (int off = 1; off < 256; off <<= 1) {
        int add = (t >= off) ? sd[t - off] : 0;
        __syncthreads();
        sd[t] += add;
        __syncthreads();
    }
    if (i < n) offs[i] = sd[t] - v;          // exclusive
    if (t == 255) bsum[blockIdx.x] = sd[t];  // block total
}

__global__ void scan2_kernel(int* __restrict__ bsum, int nb)
{
    __shared__ int sd[512];
    const int t = threadIdx.x;
    int v = (t < nb) ? bsum[t] : 0;
    sd[t] = v;
    __syncthreads();
    for (int off = 1; off < 512; off <<= 1) {
        int add = (t >= off) ? sd[t - off] : 0;
        __syncthreads();
        sd[t] += add;
        __syncthreads();
    }
    if (t < nb) bsum[t] = sd[t] - v;         // exclusive block offsets
}

__global__ void scan3_kernel(int* __restrict__ offs, int* __restrict__ cursor,
                             const int* __restrict__ bsum, int n)
{
    const int i = blockIdx.x * 256 + threadIdx.x;
    if (i < n) {
        int v = offs[i] + bsum[i >> 8];
        offs[i]   = v;
        cursor[i] = v;
    }
}

// ---------------------------------------------------------------------------
// CSR build step 3: scatter (src, eid) pairs to sorted-by-dst positions.
// ---------------------------------------------------------------------------
__global__ void __launch_bounds__(256)
scatter_kernel(const void* __restrict__ edge_index, const int* __restrict__ flag,
               int* __restrict__ cursor, int2* __restrict__ pair, int n_edges)
{
    const int is64 = flag[0];
    const int stride = gridDim.x * blockDim.x;
    for (int e = blockIdx.x * blockDim.x + threadIdx.x; e < n_edges; e += stride) {
        int src = load_idx(edge_index, e, is64);
        int dst = load_idx(edge_index, (size_t)n_edges + e, is64);
        int pos = atomicAdd(&cursor[dst], 1);
        pair[pos] = make_int2(src, e);
    }
}

// ---------------------------------------------------------------------------
// Gather-reduce: one wave per node.
//   agg_mean[i] = ( sum_e x[src_e] + (sum_e ea[e]) @ W_e + deg*b_e ) / max(deg,1)
// Written directly into d_out (consumed in-place by node_kernel).
// Lane layout: sub = lane>>4 handles edge j0+sub; k16 = lane&15 is the
// edge_attr component. x rows are read 4-per-iteration via shfl'd src.
// ---------------------------------------------------------------------------
__global__ void __launch_bounds__(256)
reduce_kernel(const float* __restrict__ x,
              const float* __restrict__ edge_attr,
              const float* __restrict__ W_e,
              const float* __restrict__ b_e,
              const int2* __restrict__ pair,
              const int* __restrict__ offs,
              const int* __restrict__ cnt,
              float* __restrict__ agg,
              int n_nodes)
{
    __shared__ float We[ED * D];
    __shared__ float be[D];
    for (int i = threadIdx.x; i < ED * D; i += blockDim.x) We[i] = W_e[i];
    if (threadIdx.x < D) be[threadIdx.x] = b_e[threadIdx.x];
    __syncthreads();

    const int lane = threadIdx.x & 63;
    const int wid  = threadIdx.x >> 6;
    const int node = blockIdx.x * 4 + wid;
    if (node >= n_nodes) return;

    const int beg = offs[node];
    const int deg = cnt[node];
    const int sub = lane >> 4;
    const int k16 = lane & 15;

    float xs  = 0.0f;   // per-lane component of sum x[src]
    float eas = 0.0f;   // per-(lane&15) component of sum edge_attr

    for (int j0 = 0; j0 < deg; j0 += 4) {
        const int jr  = j0 + sub;
        const bool act = jr < deg;
        const int jj  = beg + (act ? jr : 0);
        int2 p = pair[jj];
        if (act) eas += edge_attr[(size_t)p.y * ED + k16];
        const int mmax = min(4, deg - j0);     // wave-uniform
        for (int m = 0; m < mmax; ++m) {
            int s = __shfl(p.x, m * 16);
            xs += x[(size_t)s * D + lane];
        }
    }
    // fold the 4 subgroup partial ea sums: lane l ends with ea_sum[l&15]
    eas += __shfl_xor(eas, 16);
    eas += __shfl_xor(eas, 32);

    float acc = xs + (float)deg * be[lane];
    #pragma unroll
    for (int k = 0; k < 16; ++k)
        acc += __shfl(eas, k) * We[k * D + lane];

    const float s = 1.0f / fmaxf((float)deg, 1.0f);
    agg[(size_t)node * D + lane] = acc * s;
}

// ---------------------------------------------------------------------------
// Fallback edge phase (atomic scatter) — used only if ws_size is too small.
// ---------------------------------------------------------------------------
__global__ void __launch_bounds__(256)
edge_scatter_kernel(const float* __restrict__ x,
                    const float* __restrict__ edge_attr,
                    const float* __restrict__ W_e,
                    const float* __restrict__ b_e,
                    const void* __restrict__ edge_index,
                    const int* __restrict__ flag,
                    float* __restrict__ agg,
                    float* __restrict__ cnt,
                    int n_edges)
{
    __shared__ float We[ED * D];
    __shared__ float be[D];
    for (int i = threadIdx.x; i < ED * D; i += blockDim.x) We[i] = W_e[i];
    if (threadIdx.x < D) be[threadIdx.x] = b_e[threadIdx.x];
    __syncthreads();

    const int is64 = flag[0];
    const int lane = threadIdx.x & 63;
    const int wid  = threadIdx.x >> 6;
    const int estr = gridDim.x * 4;

    for (int e = blockIdx.x * 4 + wid; e < n_edges; e += estr) {
        int src = load_idx(edge_index, e, is64);
        int dst = load_idx(edge_index, (size_t)n_edges + e, is64);
        const float4* ea = (const float4*)(edge_attr + (size_t)e * ED);
        float4 e0 = ea[0], e1 = ea[1], e2 = ea[2], e3 = ea[3];

        float m = be[lane] + x[(size_t)src * D + lane];
        m += e0.x * We[ 0*D + lane] + e0.y * We[ 1*D + lane]
           + e0.z * We[ 2*D + lane] + e0.w * We[ 3*D + lane];
        m += e1.x * We[ 4*D + lane] + e1.y * We[ 5*D + lane]
           + e1.z * We[ 6*D + lane] + e1.w * We[ 7*D + lane];
        m += e2.x * We[ 8*D + lane] + e2.y * We[ 9*D + lane]
           + e2.z * We[10*D + lane] + e2.w * We[11*D + lane];
        m += e3.x * We[12*D + lane] + e3.y * We[13*D + lane]
           + e3.z * We[14*D + lane] + e3.w * We[15*D + lane];

        atomicAdd(&agg[(size_t)dst * D + lane], m);
        if (lane == 0) atomicAdd(&cnt[dst], 1.0f);
    }
}

__global__ void divide_kernel(float* __restrict__ agg, const float* __restrict__ cnt, int n_nodes)
{
    const int i = blockIdx.x * 256 + threadIdx.x;
    if (i < n_nodes * D) {
        float c = cnt[i >> 6];
        agg[i] *= 1.0f / fmaxf(c, 1.0f);
    }
}

// ---------------------------------------------------------------------------
// Node phase (in-place on d_out): out = agg_mean @ W_l + b_l + x @ W_r
// ---------------------------------------------------------------------------
__global__ void __launch_bounds__(256)
node_kernel(const float* __restrict__ x,
            const float* __restrict__ aggc,   // == out (in-place)
            const float* __restrict__ W_l,
            const float* __restrict__ b_l,
            const float* __restrict__ W_r,
            float* __restrict__ out,
            int n_nodes)
{
    __shared__ float Wl[D * D];
    __shared__ float Wr[D * D];
    __shared__ float bl[D];
    __shared__ float rowA[4 * D];
    __shared__ float rowX[4 * D];

    for (int i = threadIdx.x; i < D * D; i += blockDim.x) {
        Wl[i] = W_l[i];
        Wr[i] = W_r[i];
    }
    if (threadIdx.x < D) bl[threadIdx.x] = b_l[threadIdx.x];
    __syncthreads();

    const int o  = threadIdx.x & 63;
    const int il = threadIdx.x >> 6;
    const int n_tiles = (n_nodes + 3) / 4;

    for (int tile = blockIdx.x; tile < n_tiles; tile += gridDim.x) {
        const int base = tile * 4;
        const int node_of_t = base + (threadIdx.x >> 6);
        if (node_of_t < n_nodes) {
            rowA[threadIdx.x] = aggc[(size_t)base * D + threadIdx.x];
            rowX[threadIdx.x] = x[(size_t)base * D + threadIdx.x];
        }
        __syncthreads();

        const int node = base + il;
        if (node < n_nodes) {
            float acc = bl[o];
            #pragma unroll
            for (int d = 0; d < D; ++d)
                acc += rowA[il * D + d] * Wl[d * D + o]
                     + rowX[il * D + d] * Wr[d * D + o];
            out[(size_t)node * D + o] = acc;
        }
        __syncthreads();
    }
}

// ---------------------------------------------------------------------------
extern "C" void kernel_launch(void* const* d_in, const int* in_sizes, int n_in,
                              void* d_out, int out_size, void* d_ws, size_t ws_size,
                              hipStream_t stream)
{
    const float* x         = (const float*)d_in[0];
    const float* edge_attr = (const float*)d_in[1];
    const float* W_e       = (const float*)d_in[2];
    const float* b_e       = (const float*)d_in[3];
    const float* W_l       = (const float*)d_in[4];
    const float* b_l       = (const float*)d_in[5];
    const float* W_r       = (const float*)d_in[6];
    const void*  edge_index= d_in[7];

    const int n_nodes = in_sizes[0] / D;
    const int n_edges = in_sizes[1] / ED;

    float* out = (float*)d_out;

    // workspace layout (bytes)
    const size_t n_align = ((size_t)n_nodes + 255) & ~(size_t)255;
    const int    NB      = (n_nodes + 255) / 256;       // scan blocks
    const size_t o_flag  = 0;
    const size_t o_cnt   = 512;
    const size_t o_offs  = o_cnt  + n_align * 4;
    const size_t o_cur   = o_offs + n_align * 4;
    const size_t o_bsum  = o_cur  + n_align * 4;
    const size_t o_pair  = (o_bsum + (size_t)NB * 4 + 255) & ~(size_t)255;
    const size_t need    = o_pair + (size_t)n_edges * 8;

    int* flag = (int*)((char*)d_ws + o_flag);

    detect_idx64_kernel<<<1, 256, 0, stream>>>((const int*)edge_index, flag);

    if (need <= ws_size && NB <= 512) {
        int*  cnt    = (int*)((char*)d_ws + o_cnt);
        int*  offs   = (int*)((char*)d_ws + o_offs);
        int*  cursor = (int*)((char*)d_ws + o_cur);
        int*  bsum   = (int*)((char*)d_ws + o_bsum);
        int2* pair   = (int2*)((char*)d_ws + o_pair);

        hipMemsetAsync(cnt, 0, n_align * 4, stream);

        count_kernel<<<2048, 256, 0, stream>>>(edge_index, flag, cnt, n_edges);
        scan1_kernel<<<NB, 256, 0, stream>>>(cnt, offs, bsum, n_nodes);
        scan2_kernel<<<1, 512, 0, stream>>>(bsum, NB);
        scan3_kernel<<<NB, 256, 0, stream>>>(offs, cursor, bsum, n_nodes);
        scatter_kernel<<<2048, 256, 0, stream>>>(edge_index, flag, cursor, pair, n_edges);
        reduce_kernel<<<(n_nodes + 3) / 4, 256, 0, stream>>>(
            x, edge_attr, W_e, b_e, pair, offs, cnt, out, n_nodes);
    } else {
        // fallback: atomic scatter path
        float* cntf = (float*)((char*)d_ws + o_cnt);
        hipMemsetAsync(out, 0, (size_t)out_size * sizeof(float), stream);
        hipMemsetAsync(cntf, 0, (size_t)n_nodes * sizeof(float), stream);
        edge_scatter_kernel<<<4096, 256, 0, stream>>>(
            x, edge_attr, W_e, b_e, edge_index, flag, out, cntf, n_edges);
        divide_kernel<<<(n_nodes * D + 255) / 256, 256, 0, stream>>>(out, cntf, n_nodes);
    }

    node_kernel<<<2048, 256, 0, stream>>>(x, out, W_l, b_l, W_r, out, n_nodes);
}

// Round 3
// 305.373 us; speedup vs baseline: 1.2644x; 1.1069x over previous
//
#include <hip/hip_runtime.h>

#define D 64
#define ED 16

// ---------------------------------------------------------------------------
// Probe: is edge_index int64 or int32?  flag[0] = 1 -> int64, 0 -> int32.
// ---------------------------------------------------------------------------
__global__ void detect_idx64_kernel(const int* __restrict__ idx32, int* __restrict__ flag)
{
    __shared__ int any;
    if (threadIdx.x == 0) any = 0;
    __syncthreads();
    int v = 0;
    for (int i = threadIdx.x; i < 8192; i += blockDim.x)
        v |= idx32[2 * i + 1];
    if (v) atomicOr(&any, 1);
    __syncthreads();
    if (threadIdx.x == 0) flag[0] = (any == 0) ? 1 : 0;
}

__device__ __forceinline__ int load_idx(const void* p, size_t i, int is64)
{
    return is64 ? (int)((const long long*)p)[i] : ((const int*)p)[i];
}

// ---------------------------------------------------------------------------
// CSR build step 1: per-destination degree count (1 int atomic per edge).
// ---------------------------------------------------------------------------
__global__ void __launch_bounds__(256)
count_kernel(const void* __restrict__ edge_index, const int* __restrict__ flag,
             int* __restrict__ cnt, int n_edges)
{
    const int is64 = flag[0];
    const int stride = gridDim.x * blockDim.x;
    for (int e = blockIdx.x * blockDim.x + threadIdx.x; e < n_edges; e += stride) {
        int dst = load_idx(edge_index, (size_t)n_edges + e, is64);
        atomicAdd(&cnt[dst], 1);
    }
}

// ---------------------------------------------------------------------------
// CSR build step 2: two-level exclusive scan of cnt -> offs.
// ---------------------------------------------------------------------------
__global__ void scan1_kernel(const int* __restrict__ cnt, int* __restrict__ offs,
                             int* __restrict__ bsum, int n)
{
    __shared__ int sd[256];
    const int t = threadIdx.x;
    const int i = blockIdx.x * 256 + t;
    int v = (i < n) ? cnt[i] : 0;
    sd[t] = v;
    __syncthreads();
    for (int off = 1; off < 256; off <<= 1) {
        int add = (t >= off) ? sd[t - off] : 0;
        __syncthreads();
        sd[t] += add;
        __syncthreads();
    }
    if (i < n) offs[i] = sd[t] - v;          // exclusive
    if (t == 255) bsum[blockIdx.x] = sd[t];  // block total
}

__global__ void scan2_kernel(int* __restrict__ bsum, int nb)
{
    __shared__ int sd[512];
    const int t = threadIdx.x;
    int v = (t < nb) ? bsum[t] : 0;
    sd[t] = v;
    __syncthreads();
    for (int off = 1; off < 512; off <<= 1) {
        int add = (t >= off) ? sd[t - off] : 0;
        __syncthreads();
        sd[t] += add;
        __syncthreads();
    }
    if (t < nb) bsum[t] = sd[t] - v;         // exclusive block offsets
}

__global__ void scan3_kernel(int* __restrict__ offs, int* __restrict__ cursor,
                             const int* __restrict__ bsum, int n)
{
    const int i = blockIdx.x * 256 + threadIdx.x;
    if (i < n) {
        int v = offs[i] + bsum[i >> 8];
        offs[i]   = v;
        cursor[i] = v;
    }
}

// ---------------------------------------------------------------------------
// CSR build step 3: scatter (src, eid) pairs to sorted-by-dst positions.
// ---------------------------------------------------------------------------
__global__ void __launch_bounds__(256)
scatter_kernel(const void* __restrict__ edge_index, const int* __restrict__ flag,
               int* __restrict__ cursor, int2* __restrict__ pair, int n_edges)
{
    const int is64 = flag[0];
    const int stride = gridDim.x * blockDim.x;
    for (int e = blockIdx.x * blockDim.x + threadIdx.x; e < n_edges; e += stride) {
        int src = load_idx(edge_index, e, is64);
        int dst = load_idx(edge_index, (size_t)n_edges + e, is64);
        int pos = atomicAdd(&cursor[dst], 1);
        pair[pos] = make_int2(src, e);
    }
}

// ---------------------------------------------------------------------------
// Gather-reduce: one wave per node, 16 edges per iteration for MLP.
//   agg_mean[i] = ( sum_e x[src_e] + (sum_e ea[e]) @ W_e + deg*b_e ) / max(deg,1)
// Lanes 0-15 load 16 pairs coalesced; 16 independent x-row loads issued
// back-to-back (t[16] regs); edge_attr handled by 4 independent loads/lane.
// ---------------------------------------------------------------------------
__global__ void __launch_bounds__(256)
reduce_kernel(const float* __restrict__ x,
              const float* __restrict__ edge_attr,
              const float* __restrict__ W_e,
              const float* __restrict__ b_e,
              const int2* __restrict__ pair,
              const int* __restrict__ offs,
              const int* __restrict__ cnt,
              float* __restrict__ agg,
              int n_nodes)
{
    __shared__ float We[ED * D];
    __shared__ float be[D];
    for (int i = threadIdx.x; i < ED * D; i += blockDim.x) We[i] = W_e[i];
    if (threadIdx.x < D) be[threadIdx.x] = b_e[threadIdx.x];
    __syncthreads();

    const int lane = threadIdx.x & 63;
    const int wid  = threadIdx.x >> 6;
    const int node = blockIdx.x * 4 + wid;
    if (node >= n_nodes) return;

    const int beg = offs[node];
    const int deg = cnt[node];
    const int sub = lane >> 4;
    const int k16 = lane & 15;

    float xs  = 0.0f;   // per-lane component of sum x[src]
    float eas = 0.0f;   // per-(lane&15) component of sum edge_attr

    for (int j0 = 0; j0 < deg; j0 += 16) {
        const int nb = min(16, deg - j0);       // wave-uniform
        int2 p = make_int2(0, 0);
        if (lane < nb) p = pair[beg + j0 + lane];

        // 16 independent x-row gathers
        float t[16];
        #pragma unroll
        for (int m = 0; m < 16; ++m) {
            int s = __shfl(p.x, m);
            t[m] = (m < nb) ? x[(size_t)s * D + lane] : 0.0f;
        }

        // 4 independent edge_attr gathers per lane (edge m = sub + 4*mm)
        #pragma unroll
        for (int mm = 0; mm < 4; ++mm) {
            int m = sub + 4 * mm;
            int eid = __shfl(p.y, m);
            if (m < nb) eas += edge_attr[(size_t)eid * ED + k16];
        }

        #pragma unroll
        for (int m = 0; m < 16; ++m) xs += t[m];
    }
    // fold the 4 subgroup partial ea sums: lane l ends with ea_sum[l&15]
    eas += __shfl_xor(eas, 16);
    eas += __shfl_xor(eas, 32);

    float acc = xs + (float)deg * be[lane];
    #pragma unroll
    for (int k = 0; k < 16; ++k)
        acc += __shfl(eas, k) * We[k * D + lane];

    const float s = 1.0f / fmaxf((float)deg, 1.0f);
    agg[(size_t)node * D + lane] = acc * s;
}

// ---------------------------------------------------------------------------
// Fallback edge phase (atomic scatter) — used only if ws_size is too small.
// ---------------------------------------------------------------------------
__global__ void __launch_bounds__(256)
edge_scatter_kernel(const float* __restrict__ x,
                    const float* __restrict__ edge_attr,
                    const float* __restrict__ W_e,
                    const float* __restrict__ b_e,
                    const void* __restrict__ edge_index,
                    const int* __restrict__ flag,
                    float* __restrict__ agg,
                    float* __restrict__ cnt,
                    int n_edges)
{
    __shared__ float We[ED * D];
    __shared__ float be[D];
    for (int i = threadIdx.x; i < ED * D; i += blockDim.x) We[i] = W_e[i];
    if (threadIdx.x < D) be[threadIdx.x] = b_e[threadIdx.x];
    __syncthreads();

    const int is64 = flag[0];
    const int lane = threadIdx.x & 63;
    const int wid  = threadIdx.x >> 6;
    const int estr = gridDim.x * 4;

    for (int e = blockIdx.x * 4 + wid; e < n_edges; e += estr) {
        int src = load_idx(edge_index, e, is64);
        int dst = load_idx(edge_index, (size_t)n_edges + e, is64);
        const float4* ea = (const float4*)(edge_attr + (size_t)e * ED);
        float4 e0 = ea[0], e1 = ea[1], e2 = ea[2], e3 = ea[3];

        float m = be[lane] + x[(size_t)src * D + lane];
        m += e0.x * We[ 0*D + lane] + e0.y * We[ 1*D + lane]
           + e0.z * We[ 2*D + lane] + e0.w * We[ 3*D + lane];
        m += e1.x * We[ 4*D + lane] + e1.y * We[ 5*D + lane]
           + e1.z * We[ 6*D + lane] + e1.w * We[ 7*D + lane];
        m += e2.x * We[ 8*D + lane] + e2.y * We[ 9*D + lane]
           + e2.z * We[10*D + lane] + e2.w * We[11*D + lane];
        m += e3.x * We[12*D + lane] + e3.y * We[13*D + lane]
           + e3.z * We[14*D + lane] + e3.w * We[15*D + lane];

        atomicAdd(&agg[(size_t)dst * D + lane], m);
        if (lane == 0) atomicAdd(&cnt[dst], 1.0f);
    }
}

__global__ void divide_kernel(float* __restrict__ agg, const float* __restrict__ cnt, int n_nodes)
{
    const int i = blockIdx.x * 256 + threadIdx.x;
    if (i < n_nodes * D) {
        float c = cnt[i >> 6];
        agg[i] *= 1.0f / fmaxf(c, 1.0f);
    }
}

// ---------------------------------------------------------------------------
// Node phase (in-place on d_out): out = agg_mean @ W_l + b_l + x @ W_r
// One wave per block (64 threads); lane o holds columns W_l[:,o], W_r[:,o]
// in 128 VGPRs (loaded once).  Rows read as wave-uniform float4 global loads
// (single L2 request, HW-broadcast).  No LDS, 128 FMAs/node.
// NOTE: aggc may alias out (in-place) — each node read fully before written,
// by the same wave, so no __restrict on those two.
// ---------------------------------------------------------------------------
__global__ void __launch_bounds__(64)
node_kernel(const float* x,
            const float* aggc,                 // == out (in-place)
            const float* __restrict__ W_l,
            const float* __restrict__ b_l,
            const float* __restrict__ W_r,
            float* out,
            int n_nodes)
{
    const int o = threadIdx.x;                 // 0..63
    float wl[D], wr[D];
    #pragma unroll
    for (int d = 0; d < D; ++d) {              // coalesced across lanes
        wl[d] = W_l[d * D + o];
        wr[d] = W_r[d * D + o];
    }
    const float b = b_l[o];

    for (int node = blockIdx.x; node < n_nodes; node += gridDim.x) {
        const float4* A = (const float4*)(aggc + (size_t)node * D);
        const float4* X = (const float4*)(x    + (size_t)node * D);
        float acc = b;
        #pragma unroll
        for (int d0 = 0; d0 < D / 4; ++d0) {
            float4 a  = A[d0];                 // uniform addr -> 1 request
            float4 xx = X[d0];
            acc += a.x  * wl[4*d0]   + a.y  * wl[4*d0+1]
                 + a.z  * wl[4*d0+2] + a.w  * wl[4*d0+3];
            acc += xx.x * wr[4*d0]   + xx.y * wr[4*d0+1]
                 + xx.z * wr[4*d0+2] + xx.w * wr[4*d0+3];
        }
        out[(size_t)node * D + o] = acc;
    }
}

// ---------------------------------------------------------------------------
extern "C" void kernel_launch(void* const* d_in, const int* in_sizes, int n_in,
                              void* d_out, int out_size, void* d_ws, size_t ws_size,
                              hipStream_t stream)
{
    const float* x         = (const float*)d_in[0];
    const float* edge_attr = (const float*)d_in[1];
    const float* W_e       = (const float*)d_in[2];
    const float* b_e       = (const float*)d_in[3];
    const float* W_l       = (const float*)d_in[4];
    const float* b_l       = (const float*)d_in[5];
    const float* W_r       = (const float*)d_in[6];
    const void*  edge_index= d_in[7];

    const int n_nodes = in_sizes[0] / D;
    const int n_edges = in_sizes[1] / ED;

    float* out = (float*)d_out;

    // workspace layout (bytes)
    const size_t n_align = ((size_t)n_nodes + 255) & ~(size_t)255;
    const int    NB      = (n_nodes + 255) / 256;       // scan blocks
    const size_t o_flag  = 0;
    const size_t o_cnt   = 512;
    const size_t o_offs  = o_cnt  + n_align * 4;
    const size_t o_cur   = o_offs + n_align * 4;
    const size_t o_bsum  = o_cur  + n_align * 4;
    const size_t o_pair  = (o_bsum + (size_t)NB * 4 + 255) & ~(size_t)255;
    const size_t need    = o_pair + (size_t)n_edges * 8;

    int* flag = (int*)((char*)d_ws + o_flag);

    detect_idx64_kernel<<<1, 256, 0, stream>>>((const int*)edge_index, flag);

    if (need <= ws_size && NB <= 512) {
        int*  cnt    = (int*)((char*)d_ws + o_cnt);
        int*  offs   = (int*)((char*)d_ws + o_offs);
        int*  cursor = (int*)((char*)d_ws + o_cur);
        int*  bsum   = (int*)((char*)d_ws + o_bsum);
        int2* pair   = (int2*)((char*)d_ws + o_pair);

        hipMemsetAsync(cnt, 0, n_align * 4, stream);

        count_kernel<<<2048, 256, 0, stream>>>(edge_index, flag, cnt, n_edges);
        scan1_kernel<<<NB, 256, 0, stream>>>(cnt, offs, bsum, n_nodes);
        scan2_kernel<<<1, 512, 0, stream>>>(bsum, NB);
        scan3_kernel<<<NB, 256, 0, stream>>>(offs, cursor, bsum, n_nodes);
        scatter_kernel<<<2048, 256, 0, stream>>>(edge_index, flag, cursor, pair, n_edges);
        reduce_kernel<<<(n_nodes + 3) / 4, 256, 0, stream>>>(
            x, edge_attr, W_e, b_e, pair, offs, cnt, out, n_nodes);
    } else {
        // fallback: atomic scatter path
        float* cntf = (float*)((char*)d_ws + o_cnt);
        hipMemsetAsync(out, 0, (size_t)out_size * sizeof(float), stream);
        hipMemsetAsync(cntf, 0, (size_t)n_nodes * sizeof(float), stream);
        edge_scatter_kernel<<<4096, 256, 0, stream>>>(
            x, edge_attr, W_e, b_e, edge_index, flag, out, cntf, n_edges);
        divide_kernel<<<(n_nodes * D + 255) / 256, 256, 0, stream>>>(out, cntf, n_nodes);
    }

    node_kernel<<<8192, 64, 0, stream>>>(x, out, W_l, b_l, W_r, out, n_nodes);
}